// Round 7
// baseline (134.345 us; speedup 1.0000x reference)
//
#include <hip/hip_runtime.h>
#include <hip/hip_bf16.h>

#define NUM_RATINGS 10

typedef short bf16x8 __attribute__((ext_vector_type(8)));
typedef float f32x4 __attribute__((ext_vector_type(4)));

// ---- RNE f32 -> bf16 packing (static indexing only) ----
static __device__ __forceinline__ bf16x8 rne8(float4 a, float4 b) {
    float f[8] = {a.x, a.y, a.z, a.w, b.x, b.y, b.z, b.w};
    union { unsigned short us[8]; bf16x8 v; } U;
    #pragma unroll
    for (int i = 0; i < 8; ++i) {
        unsigned u = __float_as_uint(f[i]);
        U.us[i] = (unsigned short)((u + 0x7fffu + ((u >> 16) & 1u)) >> 16);
    }
    return U.v;
}

// ---------------- W -> bf16 B-fragment precompute ----------------
// Layout: wf[(r*8 + j)*64 + lane], j = tt*2 + ks.
// Lane l (eh=l&15, kg=l>>4) holds W[r][16*tt + eh][32*ks + 8*kg + i], i=0..7.
__global__ void k_wfrag(const float* __restrict__ w, bf16x8* __restrict__ wf) {
    int r = blockIdx.x;
    int lane = threadIdx.x & 63;
    int eh = lane & 15, kg = lane >> 4;
    #pragma unroll
    for (int j = 0; j < 8; ++j) {
        int tt = j >> 1, ks = j & 1;
        const float4* p = reinterpret_cast<const float4*>(
            w + ((size_t)r << 12) + (size_t)(16 * tt + eh) * 64 + 32 * ks + 8 * kg);
        wf[(r * 8 + j) * 64 + lane] = rne8(p[0], p[1]);
    }
}

#define LOADB(Bv, rr) { \
    _Pragma("unroll") \
    for (int j_ = 0; j_ < 8; ++j_) Bv[j_] = wf[((rr) * 8 + j_) * 64 + lane]; }

#define DOTILES(Bv, rr) { \
    _Pragma("unroll") \
    for (int it_ = 0; it_ < 4; ++it_) { \
        bf16x8 z_ = (bf16x8)(short)0; \
        bf16x8 am0_ = (rt[it_] == (rr)) ? a0s[it_] : z_; \
        bf16x8 am1_ = (rt[it_] == (rr)) ? a1s[it_] : z_; \
        _Pragma("unroll") \
        for (int tt_ = 0; tt_ < 4; ++tt_) { \
            acc[it_][tt_] = __builtin_amdgcn_mfma_f32_16x16x32_bf16(am0_, Bv[2 * tt_],     acc[it_][tt_], 0, 0, 0); \
            acc[it_][tt_] = __builtin_amdgcn_mfma_f32_16x16x32_bf16(am1_, Bv[2 * tt_ + 1], acc[it_][tt_], 0, 0, 0); \
        } \
    } }

// ---------------- main compute ----------------
// Natural edge order: one wave = 64 consecutive edges (4 MFMA tiles of 16).
// Speculative x-load from row=edge-id (independent of enode load) with a
// wave-uniform mismatch fix-up keeps correctness for arbitrary enode while
// removing the meta->gather serial dependency for the actual (arange) data.
// Mixed ratings: masked MFMA accumulation over 10 ratings, B-fragments
// ping-pong-prefetched from L2. D (m89): row(edge)=4*kg+rg, col=16*tt+eh.
__global__ __launch_bounds__(256) void k_main(
    const float* __restrict__ embed, const bf16x8* __restrict__ wf,
    const float* __restrict__ invc, const int* __restrict__ enode,
    const int* __restrict__ erating, float* __restrict__ out, int E) {

    int lane = threadIdx.x & 63;
    int wv = threadIdx.x >> 6;
    int eh = lane & 15, kg = lane >> 4;
    int e0 = (blockIdx.x * 4 + wv) * 64;
    if (e0 >= E) return;

    // speculative x loads (row = clamped edge id), independent of meta chain
    int etc[4];
    bf16x8 a0s[4], a1s[4];
    float4 xs0[4], xs1[4], xs2[4], xs3[4];
    #pragma unroll
    for (int it = 0; it < 4; ++it) {
        int et = e0 + 16 * it + eh;
        if (et > E - 1) et = E - 1;
        etc[it] = et;
        const float4* xp = reinterpret_cast<const float4*>(embed + ((size_t)et << 6));
        xs0[it] = xp[2 * kg];     xs1[it] = xp[2 * kg + 1];
        xs2[it] = xp[8 + 2 * kg]; xs3[it] = xp[9 + 2 * kg];
    }

    // meta loads (issued alongside the speculative x loads)
    int nd[4]; int rt[4]; float sc[4];
    #pragma unroll
    for (int it = 0; it < 4; ++it) {
        nd[it] = enode[etc[it]];
        rt[it] = erating[etc[it]];
        sc[it] = invc[etc[it]];
    }

    // first B buffer load issues before the x-dependent conversions
    bf16x8 B0[8], B1[8];
    LOADB(B0, 0)

    #pragma unroll
    for (int it = 0; it < 4; ++it) {
        a0s[it] = rne8(xs0[it], xs1[it]);
        a1s[it] = rne8(xs2[it], xs3[it]);
    }

    // mismatch fix-up (wave-uniform branch; not taken when enode==arange)
    #pragma unroll
    for (int it = 0; it < 4; ++it) {
        if (__any(nd[it] != etc[it])) {
            const float4* xp = reinterpret_cast<const float4*>(embed + ((size_t)nd[it] << 6));
            a0s[it] = rne8(xp[2 * kg], xp[2 * kg + 1]);
            a1s[it] = rne8(xp[8 + 2 * kg], xp[9 + 2 * kg]);
        }
    }

    f32x4 acc[4][4];
    #pragma unroll
    for (int it = 0; it < 4; ++it)
        #pragma unroll
        for (int tt = 0; tt < 4; ++tt) acc[it][tt] = (f32x4){0.f, 0.f, 0.f, 0.f};

    // rating loop, 2x unrolled with B ping-pong prefetch
    #pragma unroll 1
    for (int rp = 0; rp < NUM_RATINGS / 2; ++rp) {
        int r0 = 2 * rp, r1 = 2 * rp + 1;
        LOADB(B1, r1)                    // prefetch r1 while computing r0
        DOTILES(B0, r0)
        int rn = (r0 + 2 < NUM_RATINGS) ? r0 + 2 : 0;
        LOADB(B0, rn)                    // prefetch r0+2 while computing r1
        DOTILES(B1, r1)
    }

    // store: lane holds D[4kg+rg][16tt+eh]; node/scale of edge 4kg+rg via shfl
    int kg4 = kg << 2;
    #pragma unroll
    for (int it = 0; it < 4; ++it) {
        #pragma unroll
        for (int rg = 0; rg < 4; ++rg) {
            int er = e0 + 16 * it + kg4 + rg;
            int nd2 = __shfl(nd[it], kg4 + rg, 64);
            float s2 = __shfl(sc[it], kg4 + rg, 64);
            if (er < E) {
                float* po = out + ((size_t)nd2 << 6) + eh;
                __builtin_nontemporal_store(acc[it][0][rg] * s2, po);
                __builtin_nontemporal_store(acc[it][1][rg] * s2, po + 16);
                __builtin_nontemporal_store(acc[it][2][rg] * s2, po + 32);
                __builtin_nontemporal_store(acc[it][3][rg] * s2, po + 48);
            }
        }
    }
}

extern "C" void kernel_launch(void* const* d_in, const int* in_sizes, int n_in,
                              void* d_out, int out_size, void* d_ws, size_t ws_size,
                              hipStream_t stream) {
    const float* embed   = (const float*)d_in[0];
    const float* weights = (const float*)d_in[1];
    const float* invc    = (const float*)d_in[2];
    const int*   enode   = (const int*)d_in[3];
    const int*   erating = (const int*)d_in[4];
    float* out = (float*)d_out;

    int E = in_sizes[3];

    bf16x8* wf = (bf16x8*)d_ws;   // 10 * 8 * 64 * 16B = 80 KiB

    hipLaunchKernelGGL(k_wfrag, dim3(NUM_RATINGS), dim3(64), 0, stream, weights, wf);

    int waves = (E + 63) / 64;
    int blocks = (waves + 3) / 4;
    hipLaunchKernelGGL(k_main, dim3(blocks), dim3(256), 0, stream,
                       embed, wf, invc, enode, erating, out, E);
}